// Round 1
// 830.565 us; speedup vs baseline: 1.4970x; 1.4970x over previous
//
#include <hip/hip_runtime.h>

// ---------------------------------------------------------------------------
// Transformer block on MI355X. Inputs fp32, output fp32.
// GEMMs + attention via MFMA 16x16x32 bf16. Gate reads fp32 xn2 (bf16 logits
// flip top-2 selection). Attention: MFMA flash w/ in-register online softmax.
// MoE: SPARSE routed experts — gate builds per-expert token lists, experts run
// as ONE grouped-gather GLU + ONE grouped scatter down-proj (top-2 only,
// exactly equal to dense combine since non-selected weights are 0.0).
// Workspace peak ~97 MB (phase-aliased).
// ---------------------------------------------------------------------------

typedef __bf16 bf16_t;
typedef __bf16 bf16x8 __attribute__((ext_vector_type(8)));
typedef __bf16 bf16x4 __attribute__((ext_vector_type(4)));
typedef float  f32x4  __attribute__((ext_vector_type(4)));

#define GLD16(gp, lp) __builtin_amdgcn_global_load_lds(                         \
    (const __attribute__((address_space(1))) void*)(gp),                        \
    (__attribute__((address_space(3))) void*)(lp), 16, 0, 0)

// ---------------------------------------------------------------------------
// fp32 -> bf16 convert, 4 elems/thread
// ---------------------------------------------------------------------------
__global__ __launch_bounds__(256) void convert_k(
    const float* __restrict__ src, bf16_t* __restrict__ dst)
{
    size_t i = (size_t)blockIdx.x * 256 + threadIdx.x;
    float4 v = *((const float4*)src + i);
    bf16x4 o;
    o[0] = (bf16_t)v.x; o[1] = (bf16_t)v.y; o[2] = (bf16_t)v.z; o[3] = (bf16_t)v.w;
    *((bf16x4*)dst + i) = o;
}

// ---------------------------------------------------------------------------
// MFMA GEMM (m97 structure): C[m,n] = sum_k A[m,k]*W[n,k]
// mode 0: outF = acc; mode 1: outB = bf16(acc); mode 2: outF = acc + resF
// ---------------------------------------------------------------------------
__global__ __launch_bounds__(256) void gemm_bt(
    const bf16_t* __restrict__ A, const bf16_t* __restrict__ W,
    int M, int N, int K, int ldw, int mode,
    float* __restrict__ outF, bf16_t* __restrict__ outB,
    const float* __restrict__ resF)
{
    __shared__ __align__(16) bf16_t sA[128 * 64];
    __shared__ __align__(16) bf16_t sB[128 * 64];
    const int tid  = threadIdx.x;
    const int bm   = blockIdx.y * 128, bn = blockIdx.x * 128;
    const int lane = tid & 63;
    const int wv   = tid >> 6;
    const int wm   = (wv >> 1) * 64, wn = (wv & 1) * 64;
    const int lr   = lane & 15;
    const int kg   = lane >> 4;

    f32x4 acc[4][4];
    #pragma unroll
    for (int i = 0; i < 4; ++i)
        #pragma unroll
        for (int j = 0; j < 4; ++j)
            acc[i][j] = f32x4{0.f, 0.f, 0.f, 0.f};

    for (int k0 = 0; k0 < K; k0 += 64) {
        #pragma unroll
        for (int p = 0; p < 4; ++p) {
            int idx = p * 256 + tid;
            int row = idx >> 3, ch = (idx & 7) * 8;
            GLD16(A + (size_t)(bm + row) * K   + k0 + ch, sA + idx * 8);
            GLD16(W + (size_t)(bn + row) * ldw + k0 + ch, sB + idx * 8);
        }
        __syncthreads();
        #pragma unroll
        for (int ks = 0; ks < 2; ++ks) {
            bf16x8 af[4], bfr[4];
            #pragma unroll
            for (int i = 0; i < 4; ++i)
                af[i] = *(const bf16x8*)(sA + (wm + i * 16 + lr) * 64 + ks * 32 + kg * 8);
            #pragma unroll
            for (int j = 0; j < 4; ++j)
                bfr[j] = *(const bf16x8*)(sB + (wn + j * 16 + lr) * 64 + ks * 32 + kg * 8);
            #pragma unroll
            for (int i = 0; i < 4; ++i)
                #pragma unroll
                for (int j = 0; j < 4; ++j)
                    acc[i][j] = __builtin_amdgcn_mfma_f32_16x16x32_bf16(
                        af[i], bfr[j], acc[i][j], 0, 0, 0);
        }
        __syncthreads();
    }

    #pragma unroll
    for (int i = 0; i < 4; ++i) {
        #pragma unroll
        for (int j = 0; j < 4; ++j) {
            #pragma unroll
            for (int rr = 0; rr < 4; ++rr) {
                int m = bm + wm + i * 16 + kg * 4 + rr;
                int n = bn + wn + j * 16 + lr;
                size_t o = (size_t)m * N + n;
                float v = acc[i][j][rr];
                if (mode == 0)      outF[o] = v;
                else if (mode == 1) outB[o] = (bf16_t)v;
                else                outF[o] = v + resF[o];
            }
        }
    }
}

// ---------------------------------------------------------------------------
// Fused GLU GEMM (dense, used for shared expert):
// out[m,n] = bf16( silu(A@W1^T) * (A@W2^T) )
// ---------------------------------------------------------------------------
__global__ __launch_bounds__(256) void gemm_glu(
    const bf16_t* __restrict__ A, const bf16_t* __restrict__ W1,
    const bf16_t* __restrict__ W2, int M, int N, int K,
    bf16_t* __restrict__ out)
{
    __shared__ __align__(16) bf16_t sA[128 * 64];
    __shared__ __align__(16) bf16_t sB1[128 * 64];
    __shared__ __align__(16) bf16_t sB2[128 * 64];
    const int tid  = threadIdx.x;
    const int bm   = blockIdx.y * 128, bn = blockIdx.x * 128;
    const int lane = tid & 63;
    const int wv   = tid >> 6;
    const int wm   = (wv >> 1) * 64, wn = (wv & 1) * 64;
    const int lr   = lane & 15;
    const int kg   = lane >> 4;

    f32x4 acc1[4][4], acc2[4][4];
    #pragma unroll
    for (int i = 0; i < 4; ++i)
        #pragma unroll
        for (int j = 0; j < 4; ++j) {
            acc1[i][j] = f32x4{0.f, 0.f, 0.f, 0.f};
            acc2[i][j] = f32x4{0.f, 0.f, 0.f, 0.f};
        }

    for (int k0 = 0; k0 < K; k0 += 64) {
        #pragma unroll
        for (int p = 0; p < 4; ++p) {
            int idx = p * 256 + tid;
            int row = idx >> 3, ch = (idx & 7) * 8;
            GLD16(A  + (size_t)(bm + row) * K + k0 + ch, sA  + idx * 8);
            GLD16(W1 + (size_t)(bn + row) * K + k0 + ch, sB1 + idx * 8);
            GLD16(W2 + (size_t)(bn + row) * K + k0 + ch, sB2 + idx * 8);
        }
        __syncthreads();
        #pragma unroll
        for (int ks = 0; ks < 2; ++ks) {
            bf16x8 af[4], b1[4], b2[4];
            #pragma unroll
            for (int i = 0; i < 4; ++i)
                af[i] = *(const bf16x8*)(sA + (wm + i * 16 + lr) * 64 + ks * 32 + kg * 8);
            #pragma unroll
            for (int j = 0; j < 4; ++j) {
                b1[j] = *(const bf16x8*)(sB1 + (wn + j * 16 + lr) * 64 + ks * 32 + kg * 8);
                b2[j] = *(const bf16x8*)(sB2 + (wn + j * 16 + lr) * 64 + ks * 32 + kg * 8);
            }
            #pragma unroll
            for (int i = 0; i < 4; ++i)
                #pragma unroll
                for (int j = 0; j < 4; ++j) {
                    acc1[i][j] = __builtin_amdgcn_mfma_f32_16x16x32_bf16(
                        af[i], b1[j], acc1[i][j], 0, 0, 0);
                    acc2[i][j] = __builtin_amdgcn_mfma_f32_16x16x32_bf16(
                        af[i], b2[j], acc2[i][j], 0, 0, 0);
                }
        }
        __syncthreads();
    }

    #pragma unroll
    for (int i = 0; i < 4; ++i) {
        #pragma unroll
        for (int j = 0; j < 4; ++j) {
            #pragma unroll
            for (int rr = 0; rr < 4; ++rr) {
                int m = bm + wm + i * 16 + kg * 4 + rr;
                int n = bn + wn + j * 16 + lr;
                float v1 = acc1[i][j][rr], v2 = acc2[i][j][rr];
                out[(size_t)m * N + n] = (bf16_t)(v1 / (1.f + __expf(-v1)) * v2);
            }
        }
    }
}

// ---------------------------------------------------------------------------
// Grouped gathered GLU for routed experts. Grid (N/128=8, 8 experts * 32
// tile-slots). Inactive tile-slots exit. A-rows gathered via tok_list (per-
// lane global src is legal with global_load_lds). Output rows compacted at
// off[e] + t*128 (padding rows computed-but-ignored downstream).
// ---------------------------------------------------------------------------
__global__ __launch_bounds__(256) void glu_gather(
    const bf16_t* __restrict__ A, const bf16_t* __restrict__ W1,
    const bf16_t* __restrict__ W2, const int* __restrict__ tok_list,
    const int* __restrict__ cnt, const int* __restrict__ off,
    bf16_t* __restrict__ h)
{
    const int e = blockIdx.y >> 5, t = blockIdx.y & 31;
    const int ce = cnt[e];
    if (t * 128 >= ce) return;
    const int hbase = off[e] + t * 128;
    const bf16_t* W1e = W1 + (size_t)e * 1048576;
    const bf16_t* W2e = W2 + (size_t)e * 1048576;

    __shared__ __align__(16) bf16_t sA[128 * 64];
    __shared__ __align__(16) bf16_t sB1[128 * 64];
    __shared__ __align__(16) bf16_t sB2[128 * 64];
    const int tid  = threadIdx.x;
    const int bn   = blockIdx.x * 128;
    const int lane = tid & 63;
    const int wv   = tid >> 6;
    const int wm   = (wv >> 1) * 64, wn = (wv & 1) * 64;
    const int lr   = lane & 15;
    const int kg   = lane >> 4;

    // token ids for this thread's 4 staging rows (fixed across k-loop);
    // padding slots read 0 (list is memset) -> valid dummy gather
    int tok4[4];
    #pragma unroll
    for (int p = 0; p < 4; ++p)
        tok4[p] = tok_list[e * 4096 + t * 128 + p * 32 + (tid >> 3)];

    f32x4 acc1[4][4], acc2[4][4];
    #pragma unroll
    for (int i = 0; i < 4; ++i)
        #pragma unroll
        for (int j = 0; j < 4; ++j) {
            acc1[i][j] = f32x4{0.f, 0.f, 0.f, 0.f};
            acc2[i][j] = f32x4{0.f, 0.f, 0.f, 0.f};
        }

    for (int k0 = 0; k0 < 1024; k0 += 64) {
        #pragma unroll
        for (int p = 0; p < 4; ++p) {
            int idx = p * 256 + tid;
            int row = idx >> 3, ch = (idx & 7) * 8;
            GLD16(A   + (size_t)tok4[p] * 1024 + k0 + ch, sA  + idx * 8);
            GLD16(W1e + (size_t)(bn + row) * 1024 + k0 + ch, sB1 + idx * 8);
            GLD16(W2e + (size_t)(bn + row) * 1024 + k0 + ch, sB2 + idx * 8);
        }
        __syncthreads();
        #pragma unroll
        for (int ks = 0; ks < 2; ++ks) {
            bf16x8 af[4], b1[4], b2[4];
            #pragma unroll
            for (int i = 0; i < 4; ++i)
                af[i] = *(const bf16x8*)(sA + (wm + i * 16 + lr) * 64 + ks * 32 + kg * 8);
            #pragma unroll
            for (int j = 0; j < 4; ++j) {
                b1[j] = *(const bf16x8*)(sB1 + (wn + j * 16 + lr) * 64 + ks * 32 + kg * 8);
                b2[j] = *(const bf16x8*)(sB2 + (wn + j * 16 + lr) * 64 + ks * 32 + kg * 8);
            }
            #pragma unroll
            for (int i = 0; i < 4; ++i)
                #pragma unroll
                for (int j = 0; j < 4; ++j) {
                    acc1[i][j] = __builtin_amdgcn_mfma_f32_16x16x32_bf16(
                        af[i], b1[j], acc1[i][j], 0, 0, 0);
                    acc2[i][j] = __builtin_amdgcn_mfma_f32_16x16x32_bf16(
                        af[i], b2[j], acc2[i][j], 0, 0, 0);
                }
        }
        __syncthreads();
    }

    #pragma unroll
    for (int i = 0; i < 4; ++i) {
        #pragma unroll
        for (int j = 0; j < 4; ++j) {
            #pragma unroll
            for (int rr = 0; rr < 4; ++rr) {
                int rl = wm + i * 16 + kg * 4 + rr;        // row in tile
                int n  = bn + wn + j * 16 + lr;
                float v1 = acc1[i][j][rr], v2 = acc2[i][j][rr];
                h[(size_t)(hbase + rl) * 1024 + n] =
                    (bf16_t)(v1 / (1.f + __expf(-v1)) * v2);
            }
        }
    }
}

// ---------------------------------------------------------------------------
// Grouped down-proj with weighted scatter-add into y. Same tiling as
// glu_gather; only rows with t*128+rl < cnt[e] are committed (atomicAdd f32,
// device-scope; each y element hit by at most 2 experts).
// ---------------------------------------------------------------------------
__global__ __launch_bounds__(256) void down_gather(
    const bf16_t* __restrict__ h, const bf16_t* __restrict__ Wp,
    const int* __restrict__ tok_list, const float* __restrict__ w_list,
    const int* __restrict__ cnt, const int* __restrict__ off,
    float* __restrict__ y)
{
    const int e = blockIdx.y >> 5, t = blockIdx.y & 31;
    const int ce = cnt[e];
    if (t * 128 >= ce) return;
    const int hbase = off[e] + t * 128;
    const bf16_t* We = Wp + (size_t)e * 1048576;

    __shared__ __align__(16) bf16_t sA[128 * 64];
    __shared__ __align__(16) bf16_t sB[128 * 64];
    const int tid  = threadIdx.x;
    const int bn   = blockIdx.x * 128;
    const int lane = tid & 63;
    const int wv   = tid >> 6;
    const int wm   = (wv >> 1) * 64, wn = (wv & 1) * 64;
    const int lr   = lane & 15;
    const int kg   = lane >> 4;

    f32x4 acc[4][4];
    #pragma unroll
    for (int i = 0; i < 4; ++i)
        #pragma unroll
        for (int j = 0; j < 4; ++j)
            acc[i][j] = f32x4{0.f, 0.f, 0.f, 0.f};

    for (int k0 = 0; k0 < 1024; k0 += 64) {
        #pragma unroll
        for (int p = 0; p < 4; ++p) {
            int idx = p * 256 + tid;
            int row = idx >> 3, ch = (idx & 7) * 8;
            GLD16(h  + (size_t)(hbase + row) * 1024 + k0 + ch, sA + idx * 8);
            GLD16(We + (size_t)(bn + row) * 1024 + k0 + ch,    sB + idx * 8);
        }
        __syncthreads();
        #pragma unroll
        for (int ks = 0; ks < 2; ++ks) {
            bf16x8 af[4], bfr[4];
            #pragma unroll
            for (int i = 0; i < 4; ++i)
                af[i] = *(const bf16x8*)(sA + (wm + i * 16 + lr) * 64 + ks * 32 + kg * 8);
            #pragma unroll
            for (int j = 0; j < 4; ++j)
                bfr[j] = *(const bf16x8*)(sB + (wn + j * 16 + lr) * 64 + ks * 32 + kg * 8);
            #pragma unroll
            for (int i = 0; i < 4; ++i)
                #pragma unroll
                for (int j = 0; j < 4; ++j)
                    acc[i][j] = __builtin_amdgcn_mfma_f32_16x16x32_bf16(
                        af[i], bfr[j], acc[i][j], 0, 0, 0);
        }
        __syncthreads();
    }

    #pragma unroll
    for (int i = 0; i < 4; ++i) {
        #pragma unroll
        for (int rr = 0; rr < 4; ++rr) {
            int rl = t * 128 + wm + i * 16 + kg * 4 + rr;  // row in expert seg
            if (rl < ce) {
                int   tok = tok_list[e * 4096 + rl];
                float wgt = w_list[e * 4096 + rl];
                #pragma unroll
                for (int j = 0; j < 4; ++j) {
                    int n = bn + wn + j * 16 + lr;
                    atomicAdd(&y[(size_t)tok * 1024 + n], wgt * acc[i][j][rr]);
                }
            }
        }
    }
}

// ---------------------------------------------------------------------------
// RMSNorm: fp32 src -> bf16 dst (+ optional fp32 dstF), row length 1024
// ---------------------------------------------------------------------------
__global__ __launch_bounds__(256) void rmsnorm_k(
    const float* __restrict__ src, const float* __restrict__ w,
    bf16_t* __restrict__ dst, float* __restrict__ dstF)
{
    const int row = blockIdx.x, tid = threadIdx.x;
    float4 t4 = *((const float4*)src + (size_t)row * 256 + tid);
    float ssum = t4.x*t4.x + t4.y*t4.y + t4.z*t4.z + t4.w*t4.w;
    #pragma unroll
    for (int off = 32; off > 0; off >>= 1) ssum += __shfl_down(ssum, off);
    __shared__ float red[4];
    if ((tid & 63) == 0) red[tid >> 6] = ssum;
    __syncthreads();
    float total = red[0] + red[1] + red[2] + red[3];
    float rms = rsqrtf(total * (1.0f / 1024.0f) + 1e-6f);
    float4 w4 = *((const float4*)w + tid);
    float4 f4;
    f4.x = t4.x * rms * w4.x;
    f4.y = t4.y * rms * w4.y;
    f4.z = t4.z * rms * w4.z;
    f4.w = t4.w * rms * w4.w;
    bf16x4 o4;
    o4[0] = (bf16_t)f4.x; o4[1] = (bf16_t)f4.y;
    o4[2] = (bf16_t)f4.z; o4[3] = (bf16_t)f4.w;
    *((bf16x4*)dst + (size_t)row * 256 + tid) = o4;
    if (dstF) *((float4*)dstF + (size_t)row * 256 + tid) = f4;
}

// ---------------------------------------------------------------------------
// RoPE in-place on bf16 buffer (4096 x nh*64); freq fp32 (1024 x 32 x 2)
// ---------------------------------------------------------------------------
__global__ __launch_bounds__(256) void rope_k(
    bf16_t* __restrict__ buf, const float* __restrict__ fc, int nh)
{
    int idx = blockIdx.x * 256 + threadIdx.x;
    int pr = idx & 31;
    int hn = idx >> 5;
    int h  = hn % nh;
    int n  = hn / nh;
    int tpos = n & 1023;
    const float* f = fc + ((size_t)tpos * 32 + pr) * 2;
    float c = f[0], s = f[1];
    size_t base = ((size_t)n * nh + h) * 64 + pr * 2;
    float x0 = (float)buf[base], x1 = (float)buf[base + 1];
    buf[base]     = (bf16_t)(x0 * c - x1 * s);
    buf[base + 1] = (bf16_t)(x1 * c + x0 * s);
}

// ---------------------------------------------------------------------------
// V transpose: vb (4096 x 256, [token][kvh*64+d]) -> vt [(b*4+kvh)*64+d][1024]
// ---------------------------------------------------------------------------
__global__ __launch_bounds__(256) void transpose_v(
    const bf16_t* __restrict__ vb, bf16_t* __restrict__ vt)
{
    __shared__ bf16_t tile[64][72];
    const int tt = blockIdx.x, kvh = blockIdx.y, b = blockIdx.z;
    const int tid = threadIdx.x;
    {
        int r = tid >> 2, c = (tid & 3) * 16;
        const bf16_t* src = vb + ((size_t)(b * 1024 + tt * 64 + r)) * 256 + kvh * 64 + c;
        bf16x8 v0 = *(const bf16x8*)src;
        bf16x8 v1 = *(const bf16x8*)(src + 8);
        *(bf16x8*)&tile[r][c] = v0;
        *(bf16x8*)&tile[r][c + 8] = v1;
    }
    __syncthreads();
    {
        int d = tid >> 2, t4 = (tid & 3) * 16;
        bf16_t* dst = vt + ((size_t)((b * 4 + kvh) * 64 + d)) * 1024 + tt * 64 + t4;
        bf16x8 o0, o1;
        #pragma unroll
        for (int u = 0; u < 8; ++u) {
            o0[u] = tile[t4 + u][d];
            o1[u] = tile[t4 + 8 + u][d];
        }
        *(bf16x8*)dst = o0;
        *(bf16x8*)(dst + 8) = o1;
    }
}

// ---------------------------------------------------------------------------
// MFMA flash attention, causal GQA. Grid (qt=16, h=16, b=4), 256 thr = 4 waves.
// ---------------------------------------------------------------------------
__global__ __launch_bounds__(256) void attn_mfma(
    const bf16_t* __restrict__ qb, const bf16_t* __restrict__ kb,
    const bf16_t* __restrict__ vt, bf16_t* __restrict__ ob)
{
    const int qt = blockIdx.x, h = blockIdx.y, b = blockIdx.z;
    const int kvh = h >> 2;
    __shared__ __align__(16) bf16_t sK[64 * 64];
    __shared__ __align__(16) bf16_t sVt[64 * 64];
    __shared__ __align__(16) bf16_t sP[64 * 72];
    const int tid  = threadIdx.x;
    const int w    = tid >> 6;
    const int lane = tid & 63;
    const int lr   = lane & 15;
    const int kg   = lane >> 4;

    bf16x8 qf[2];
    {
        const bf16_t* qrow = qb + ((size_t)(b * 1024 + qt * 64 + w * 16 + lr)) * 1024 + h * 64;
        qf[0] = *(const bf16x8*)(qrow + kg * 8);
        qf[1] = *(const bf16x8*)(qrow + 32 + kg * 8);
    }
    float m_run[4], l_run[4];
    f32x4 o_acc[4];
    #pragma unroll
    for (int rr = 0; rr < 4; ++rr) { m_run[rr] = -1.0e30f; l_run[rr] = 0.f; }
    #pragma unroll
    for (int dt = 0; dt < 4; ++dt) o_acc[dt] = f32x4{0.f, 0.f, 0.f, 0.f};

    for (int kt = 0; kt <= qt; ++kt) {
        #pragma unroll
        for (int p = 0; p < 2; ++p) {
            int idx = p * 256 + tid;
            int row = idx >> 3, ch = (idx & 7) * 8;
            GLD16(kb + ((size_t)(b * 1024 + kt * 64 + row)) * 256 + kvh * 64 + ch,
                  sK + idx * 8);
            GLD16(vt + ((size_t)((b * 4 + kvh) * 64 + row)) * 1024 + kt * 64 + ch,
                  sVt + idx * 8);
        }
        __syncthreads();

        f32x4 sfr[4];
        #pragma unroll
        for (int j = 0; j < 4; ++j) {
            sfr[j] = f32x4{0.f, 0.f, 0.f, 0.f};
            #pragma unroll
            for (int ks = 0; ks < 2; ++ks) {
                bf16x8 bf = *(const bf16x8*)(sK + (j * 16 + lr) * 64 + ks * 32 + kg * 8);
                sfr[j] = __builtin_amdgcn_mfma_f32_16x16x32_bf16(qf[ks], bf, sfr[j], 0, 0, 0);
            }
        }
        const int rowg = qt * 64 + w * 16 + kg * 4;
        float mnew[4];
        #pragma unroll
        for (int rr = 0; rr < 4; ++rr) mnew[rr] = m_run[rr];
        #pragma unroll
        for (int j = 0; j < 4; ++j) {
            int colg = kt * 64 + j * 16 + lr;
            #pragma unroll
            for (int rr = 0; rr < 4; ++rr) {
                float s = sfr[j][rr] * 0.125f;
                if (colg > rowg + rr) s = -1.0e30f;
                sfr[j][rr] = s;
                mnew[rr] = fmaxf(mnew[rr], s);
            }
        }
        #pragma unroll
        for (int off = 1; off < 16; off <<= 1)
            #pragma unroll
            for (int rr = 0; rr < 4; ++rr)
                mnew[rr] = fmaxf(mnew[rr], __shfl_xor(mnew[rr], off, 64));
        float alpha[4], lpart[4];
        #pragma unroll
        for (int rr = 0; rr < 4; ++rr) {
            alpha[rr] = __expf(m_run[rr] - mnew[rr]);
            lpart[rr] = 0.f;
        }
        #pragma unroll
        for (int j = 0; j < 4; ++j)
            #pragma unroll
            for (int rr = 0; rr < 4; ++rr) {
                float p = __expf(sfr[j][rr] - mnew[rr]);
                sfr[j][rr] = p;
                lpart[rr] += p;
            }
        #pragma unroll
        for (int j = 0; j < 4; ++j)
            #pragma unroll
            for (int rr = 0; rr < 4; ++rr)
                sP[(w * 16 + kg * 4 + rr) * 72 + j * 16 + lr] = (bf16_t)sfr[j][rr];
        #pragma unroll
        for (int off = 1; off < 16; off <<= 1)
            #pragma unroll
            for (int rr = 0; rr < 4; ++rr)
                lpart[rr] += __shfl_xor(lpart[rr], off, 64);
        #pragma unroll
        for (int rr = 0; rr < 4; ++rr) {
            l_run[rr] = l_run[rr] * alpha[rr] + lpart[rr];
            m_run[rr] = mnew[rr];
        }
        #pragma unroll
        for (int dt = 0; dt < 4; ++dt)
            #pragma unroll
            for (int rr = 0; rr < 4; ++rr)
                o_acc[dt][rr] *= alpha[rr];
        #pragma unroll
        for (int ks = 0; ks < 2; ++ks) {
            bf16x8 af = *(const bf16x8*)(sP + (w * 16 + lr) * 72 + ks * 32 + kg * 8);
            #pragma unroll
            for (int dt = 0; dt < 4; ++dt) {
                bf16x8 bf = *(const bf16x8*)(sVt + (dt * 16 + lr) * 64 + ks * 32 + kg * 8);
                o_acc[dt] = __builtin_amdgcn_mfma_f32_16x16x32_bf16(af, bf, o_acc[dt], 0, 0, 0);
            }
        }
        __syncthreads();
    }

    float inv[4];
    #pragma unroll
    for (int rr = 0; rr < 4; ++rr) inv[rr] = 1.0f / l_run[rr];
    #pragma unroll
    for (int dt = 0; dt < 4; ++dt)
        #pragma unroll
        for (int rr = 0; rr < 4; ++rr) {
            int tok = qt * 64 + w * 16 + kg * 4 + rr;
            ob[((size_t)(b * 1024 + tok)) * 1024 + h * 64 + dt * 16 + lr] =
                (bf16_t)(o_acc[dt][rr] * inv[rr]);
        }
}

// ---------------------------------------------------------------------------
// Gate: fp32 logits (matches reference top-2); scores fp32; builds per-expert
// token lists (tok_list/w_list) via atomic counters.
// ---------------------------------------------------------------------------
__global__ __launch_bounds__(256) void gate_kernel(
    const float* __restrict__ xn2, const float* __restrict__ gw,
    float* __restrict__ scores, int* __restrict__ tok_list,
    float* __restrict__ w_list, int* __restrict__ cnt)
{
    const int lane = threadIdx.x & 63;
    const int n = blockIdx.x * 4 + (threadIdx.x >> 6);
    const float* xr = xn2 + (size_t)n * 1024;
    float acc[8];
    #pragma unroll
    for (int e = 0; e < 8; ++e) acc[e] = 0.f;
    for (int d = lane; d < 1024; d += 64) {
        float xv = xr[d];
        #pragma unroll
        for (int e = 0; e < 8; ++e) acc[e] += xv * gw[e * 1024 + d];
    }
    #pragma unroll
    for (int e = 0; e < 8; ++e)
        #pragma unroll
        for (int off = 32; off > 0; off >>= 1) acc[e] += __shfl_down(acc[e], off);
    if (lane == 0) {
        float mx = acc[0];
        #pragma unroll
        for (int e = 1; e < 8; ++e) mx = fmaxf(mx, acc[e]);
        float p[8], sum = 0.f;
        #pragma unroll
        for (int e = 0; e < 8; ++e) { p[e] = __expf(acc[e] - mx); sum += p[e]; }
        float inv = 1.0f / sum;
        #pragma unroll
        for (int e = 0; e < 8; ++e) p[e] *= inv;
        int i1 = 0;
        #pragma unroll
        for (int e = 1; e < 8; ++e) if (p[e] > p[i1]) i1 = e;
        int i2 = (i1 == 0) ? 1 : 0;
        #pragma unroll
        for (int e = 0; e < 8; ++e) if (e != i1 && p[e] > p[i2]) i2 = e;
        #pragma unroll
        for (int e = 0; e < 8; ++e) scores[(size_t)n * 8 + e] = acc[e];
        int pos1 = atomicAdd(&cnt[i1], 1);
        tok_list[i1 * 4096 + pos1] = n;
        w_list[i1 * 4096 + pos1]   = p[i1];
        int pos2 = atomicAdd(&cnt[i2], 1);
        tok_list[i2 * 4096 + pos2] = n;
        w_list[i2 * 4096 + pos2]   = p[i2];
    }
}

// ---------------------------------------------------------------------------
// Routing plan: 128-padded prefix offsets per expert (total <= 9216 rows)
// ---------------------------------------------------------------------------
__global__ void plan_k(const int* __restrict__ cnt, int* __restrict__ off)
{
    if (threadIdx.x == 0) {
        int run = 0;
        for (int e = 0; e < 8; ++e) {
            off[e] = run;
            run += (cnt[e] + 127) & ~127;
        }
    }
}

// ---------------------------------------------------------------------------
// out = x1 + y (fp32)
// ---------------------------------------------------------------------------
__global__ __launch_bounds__(256) void finalize_k(
    const float* __restrict__ x1, const float* __restrict__ y, float* __restrict__ out)
{
    size_t i = (size_t)blockIdx.x * 256 + threadIdx.x;
    float4 a = *((const float4*)x1 + i);
    float4 b = *((const float4*)y + i);
    float4 o4;
    o4.x = a.x + b.x; o4.y = a.y + b.y; o4.z = a.z + b.z; o4.w = a.w + b.w;
    *((float4*)out + i) = o4;
}

// ---------------------------------------------------------------------------
extern "C" void kernel_launch(void* const* d_in, const int* in_sizes, int n_in,
                              void* d_out, int out_size, void* d_ws, size_t ws_size,
                              hipStream_t stream)
{
    const float* x   = (const float*)d_in[0];
    const float* fc  = (const float*)d_in[1];
    const float* n1w = (const float*)d_in[4];
    const float* wq  = (const float*)d_in[5];
    const float* wk  = (const float*)d_in[6];
    const float* wv  = (const float*)d_in[7];
    const float* wo  = (const float*)d_in[8];
    const float* n2w = (const float*)d_in[9];
    const float* gw  = (const float*)d_in[10];
    const float* ew1 = (const float*)d_in[11];
    const float* ew2 = (const float*)d_in[12];
    const float* ewp = (const float*)d_in[13];
    const float* sw1 = (const float*)d_in[14];
    const float* sw2 = (const float*)d_in[15];
    const float* swp = (const float*)d_in[16];

    // ---- workspace (peak ~97 MB; phase-aliased) ----
    const size_t MB = 1024 * 1024;
    char* ws = (char*)d_ws;
    bf16_t* xnb  = (bf16_t*)(ws + 0);        // [0,8)   xn / xn2 bf16
    float*  x1   = (float*) (ws + 8 * MB);   // [8,24)  residual-1 fp32
    float*  y    = (float*) (ws + 24 * MB);  // [24,40) MoE accum fp32
    char*   slotA= ws + 40 * MB;             // [40,56) attn-w | xn2f | sh-hb | ew1b | ewpb
    bf16_t* h    = (bf16_t*)(ws + 56 * MB);  // [56,74) expert GLU out (9216 x 1024)
    char*   lists= ws + 74 * MB;             // [74,74.25) routing lists
    int*    tok_list = (int*)lists;                   // 8*4096 int
    float*  w_list   = (float*)(lists + 131072);      // 8*4096 float
    int*    cnt      = (int*)(lists + 262144);        // 8 int
    int*    off      = (int*)(lists + 262208);        // 8 int
    bf16_t* qb   = (bf16_t*)(ws + 75 * MB);  // [75,83) attn phase
    bf16_t* kb   = (bf16_t*)(ws + 83 * MB);  // [83,85)
    bf16_t* vb   = (bf16_t*)(ws + 85 * MB);  // [85,87)
    bf16_t* ob   = (bf16_t*)(ws + 87 * MB);  // [87,95)
    bf16_t* vt   = (bf16_t*)(ws + 95 * MB);  // [95,97) V transposed

    float* outp   = (float*)d_out;
    float* scores = outp + (size_t)4096 * 1024;

    auto conv = [&](const float* s, bf16_t* d, size_t cntN) {
        convert_k<<<cntN / 1024, 256, 0, stream>>>(s, d);
    };
    auto gemm = [&](const bf16_t* A, const bf16_t* W, int M, int N, int K, int ldw,
                    int mode, float* oF, bf16_t* oB, const float* res) {
        gemm_bt<<<dim3(N / 128, M / 128), 256, 0, stream>>>(
            A, W, M, N, K, ldw, mode, oF, oB, res);
    };
    auto glu = [&](const bf16_t* A, const bf16_t* W1, const bf16_t* W2,
                   int M, int N, int K, bf16_t* o) {
        gemm_glu<<<dim3(N / 128, M / 128), 256, 0, stream>>>(A, W1, W2, M, N, K, o);
    };

    // ---- attention ----
    bf16_t* wqb = (bf16_t*)slotA;            // dead once rmsnorm2 writes xn2f
    bf16_t* wkb = wqb + 1048576;
    bf16_t* wvb = wkb + 262144;
    bf16_t* wob = wvb + 262144;
    conv(wq, wqb, 1048576);
    conv(wk, wkb, 262144);
    conv(wv, wvb, 262144);
    conv(wo, wob, 1048576);

    rmsnorm_k<<<4096, 256, 0, stream>>>(x, n1w, xnb, nullptr);
    gemm(xnb, wqb, 4096, 1024, 1024, 1024, 1, nullptr, qb, nullptr);
    gemm(xnb, wkb, 4096, 256, 1024, 1024, 1, nullptr, kb, nullptr);
    gemm(xnb, wvb, 4096, 256, 1024, 1024, 1, nullptr, vb, nullptr);
    rope_k<<<(4096 * 16 * 32) / 256, 256, 0, stream>>>(qb, fc, 16);
    rope_k<<<(4096 * 4 * 32) / 256, 256, 0, stream>>>(kb, fc, 4);
    transpose_v<<<dim3(16, 4, 4), 256, 0, stream>>>(vb, vt);
    attn_mfma<<<dim3(16, 16, 4), 256, 0, stream>>>(qb, kb, vt, ob);
    gemm(ob, wob, 4096, 1024, 1024, 1024, 2, x1, nullptr, x);

    // ---- MoE: norm + gate + routing plan ----
    float* xn2f = (float*)slotA;             // overwrites attn weights (dead)
    rmsnorm_k<<<4096, 256, 0, stream>>>(x1, n2w, xnb, xn2f);
    hipMemsetAsync(lists, 0, 262272, stream);   // tok_list + w_list + cnt
    gate_kernel<<<1024, 256, 0, stream>>>(xn2f, gw, scores, tok_list, w_list, cnt);
    plan_k<<<1, 64, 0, stream>>>(cnt, off);

    // ---- shared expert (dense) ----
    bf16_t* sw1b = (bf16_t*)(ws + 75 * MB);  // overwrites attn bufs (dead)
    bf16_t* sw2b = sw1b + 2097152;
    bf16_t* swpb = sw2b + 2097152;
    conv(sw1, sw1b, 2097152);
    conv(sw2, sw2b, 2097152);
    conv(swp, swpb, 2097152);
    bf16_t* hb = (bf16_t*)slotA;             // overwrites xn2f (dead after gate)
    glu(xnb, sw1b, sw2b, 4096, 2048, 1024, hb);
    gemm(hb, swpb, 4096, 1024, 2048, 2048, 0, y, nullptr, nullptr);

    // ---- routed experts (sparse, grouped single launches) ----
    bf16_t* ew1b = (bf16_t*)slotA;           // overwrites shared hb (dead)
    bf16_t* ew2b = (bf16_t*)(ws + 75 * MB);  // overwrites shared weights (dead)
    conv(ew1, ew1b, 8388608);
    conv(ew2, ew2b, 8388608);
    glu_gather<<<dim3(8, 256), 256, 0, stream>>>(xnb, ew1b, ew2b,
                                                 tok_list, cnt, off, h);
    bf16_t* ewpb = (bf16_t*)slotA;           // overwrites ew1b (dead after GLU)
    conv(ewp, ewpb, 8388608);
    down_gather<<<dim3(8, 256), 256, 0, stream>>>(h, ewpb,
                                                  tok_list, w_list, cnt, off, y);

    finalize_k<<<(4096 * 1024) / 1024, 256, 0, stream>>>(x1, y, outp);
    (void)in_sizes; (void)n_in; (void)out_size; (void)ws_size;
}

// Round 2
// 740.716 us; speedup vs baseline: 1.6785x; 1.1213x over previous
//
#include <hip/hip_runtime.h>

// ---------------------------------------------------------------------------
// Transformer block on MI355X. Inputs fp32, output fp32.
// GEMMs + attention via MFMA 16x16x32 bf16. Attention: MFMA flash w/
// in-register online softmax. MoE: SPARSE routed experts. Gate is FUSED into
// rmsnorm2 (fp32 logits in-register; round-8 lesson: bf16 logits flip top-2).
// Routing lists built atomically-free: one block per expert, ballot+prefix
// (the old per-token atomicAdd on an 8-int cnt[] serialized 8192 same-line
// atomics -> 107 us). Workspace peak ~97 MB (phase-aliased).
// ---------------------------------------------------------------------------

typedef __bf16 bf16_t;
typedef __bf16 bf16x8 __attribute__((ext_vector_type(8)));
typedef __bf16 bf16x4 __attribute__((ext_vector_type(4)));
typedef float  f32x4  __attribute__((ext_vector_type(4)));

#define GLD16(gp, lp) __builtin_amdgcn_global_load_lds(                         \
    (const __attribute__((address_space(1))) void*)(gp),                        \
    (__attribute__((address_space(3))) void*)(lp), 16, 0, 0)

// ---------------------------------------------------------------------------
// fp32 -> bf16 convert, 4 elems/thread
// ---------------------------------------------------------------------------
__global__ __launch_bounds__(256) void convert_k(
    const float* __restrict__ src, bf16_t* __restrict__ dst)
{
    size_t i = (size_t)blockIdx.x * 256 + threadIdx.x;
    float4 v = *((const float4*)src + i);
    bf16x4 o;
    o[0] = (bf16_t)v.x; o[1] = (bf16_t)v.y; o[2] = (bf16_t)v.z; o[3] = (bf16_t)v.w;
    *((bf16x4*)dst + i) = o;
}

// ---------------------------------------------------------------------------
// MFMA GEMM (m97 structure): C[m,n] = sum_k A[m,k]*W[n,k]
// mode 0: outF = acc; mode 1: outB = bf16(acc); mode 2: outF = acc + resF
// ---------------------------------------------------------------------------
__global__ __launch_bounds__(256) void gemm_bt(
    const bf16_t* __restrict__ A, const bf16_t* __restrict__ W,
    int M, int N, int K, int ldw, int mode,
    float* __restrict__ outF, bf16_t* __restrict__ outB,
    const float* __restrict__ resF)
{
    __shared__ __align__(16) bf16_t sA[128 * 64];
    __shared__ __align__(16) bf16_t sB[128 * 64];
    const int tid  = threadIdx.x;
    const int bm   = blockIdx.y * 128, bn = blockIdx.x * 128;
    const int lane = tid & 63;
    const int wv   = tid >> 6;
    const int wm   = (wv >> 1) * 64, wn = (wv & 1) * 64;
    const int lr   = lane & 15;
    const int kg   = lane >> 4;

    f32x4 acc[4][4];
    #pragma unroll
    for (int i = 0; i < 4; ++i)
        #pragma unroll
        for (int j = 0; j < 4; ++j)
            acc[i][j] = f32x4{0.f, 0.f, 0.f, 0.f};

    for (int k0 = 0; k0 < K; k0 += 64) {
        #pragma unroll
        for (int p = 0; p < 4; ++p) {
            int idx = p * 256 + tid;
            int row = idx >> 3, ch = (idx & 7) * 8;
            GLD16(A + (size_t)(bm + row) * K   + k0 + ch, sA + idx * 8);
            GLD16(W + (size_t)(bn + row) * ldw + k0 + ch, sB + idx * 8);
        }
        __syncthreads();
        #pragma unroll
        for (int ks = 0; ks < 2; ++ks) {
            bf16x8 af[4], bfr[4];
            #pragma unroll
            for (int i = 0; i < 4; ++i)
                af[i] = *(const bf16x8*)(sA + (wm + i * 16 + lr) * 64 + ks * 32 + kg * 8);
            #pragma unroll
            for (int j = 0; j < 4; ++j)
                bfr[j] = *(const bf16x8*)(sB + (wn + j * 16 + lr) * 64 + ks * 32 + kg * 8);
            #pragma unroll
            for (int i = 0; i < 4; ++i)
                #pragma unroll
                for (int j = 0; j < 4; ++j)
                    acc[i][j] = __builtin_amdgcn_mfma_f32_16x16x32_bf16(
                        af[i], bfr[j], acc[i][j], 0, 0, 0);
        }
        __syncthreads();
    }

    #pragma unroll
    for (int i = 0; i < 4; ++i) {
        #pragma unroll
        for (int j = 0; j < 4; ++j) {
            #pragma unroll
            for (int rr = 0; rr < 4; ++rr) {
                int m = bm + wm + i * 16 + kg * 4 + rr;
                int n = bn + wn + j * 16 + lr;
                size_t o = (size_t)m * N + n;
                float v = acc[i][j][rr];
                if (mode == 0)      outF[o] = v;
                else if (mode == 1) outB[o] = (bf16_t)v;
                else                outF[o] = v + resF[o];
            }
        }
    }
}

// ---------------------------------------------------------------------------
// Fused GLU GEMM (dense, used for shared expert):
// out[m,n] = bf16( silu(A@W1^T) * (A@W2^T) )
// ---------------------------------------------------------------------------
__global__ __launch_bounds__(256) void gemm_glu(
    const bf16_t* __restrict__ A, const bf16_t* __restrict__ W1,
    const bf16_t* __restrict__ W2, int M, int N, int K,
    bf16_t* __restrict__ out)
{
    __shared__ __align__(16) bf16_t sA[128 * 64];
    __shared__ __align__(16) bf16_t sB1[128 * 64];
    __shared__ __align__(16) bf16_t sB2[128 * 64];
    const int tid  = threadIdx.x;
    const int bm   = blockIdx.y * 128, bn = blockIdx.x * 128;
    const int lane = tid & 63;
    const int wv   = tid >> 6;
    const int wm   = (wv >> 1) * 64, wn = (wv & 1) * 64;
    const int lr   = lane & 15;
    const int kg   = lane >> 4;

    f32x4 acc1[4][4], acc2[4][4];
    #pragma unroll
    for (int i = 0; i < 4; ++i)
        #pragma unroll
        for (int j = 0; j < 4; ++j) {
            acc1[i][j] = f32x4{0.f, 0.f, 0.f, 0.f};
            acc2[i][j] = f32x4{0.f, 0.f, 0.f, 0.f};
        }

    for (int k0 = 0; k0 < K; k0 += 64) {
        #pragma unroll
        for (int p = 0; p < 4; ++p) {
            int idx = p * 256 + tid;
            int row = idx >> 3, ch = (idx & 7) * 8;
            GLD16(A  + (size_t)(bm + row) * K + k0 + ch, sA  + idx * 8);
            GLD16(W1 + (size_t)(bn + row) * K + k0 + ch, sB1 + idx * 8);
            GLD16(W2 + (size_t)(bn + row) * K + k0 + ch, sB2 + idx * 8);
        }
        __syncthreads();
        #pragma unroll
        for (int ks = 0; ks < 2; ++ks) {
            bf16x8 af[4], b1[4], b2[4];
            #pragma unroll
            for (int i = 0; i < 4; ++i)
                af[i] = *(const bf16x8*)(sA + (wm + i * 16 + lr) * 64 + ks * 32 + kg * 8);
            #pragma unroll
            for (int j = 0; j < 4; ++j) {
                b1[j] = *(const bf16x8*)(sB1 + (wn + j * 16 + lr) * 64 + ks * 32 + kg * 8);
                b2[j] = *(const bf16x8*)(sB2 + (wn + j * 16 + lr) * 64 + ks * 32 + kg * 8);
            }
            #pragma unroll
            for (int i = 0; i < 4; ++i)
                #pragma unroll
                for (int j = 0; j < 4; ++j) {
                    acc1[i][j] = __builtin_amdgcn_mfma_f32_16x16x32_bf16(
                        af[i], b1[j], acc1[i][j], 0, 0, 0);
                    acc2[i][j] = __builtin_amdgcn_mfma_f32_16x16x32_bf16(
                        af[i], b2[j], acc2[i][j], 0, 0, 0);
                }
        }
        __syncthreads();
    }

    #pragma unroll
    for (int i = 0; i < 4; ++i) {
        #pragma unroll
        for (int j = 0; j < 4; ++j) {
            #pragma unroll
            for (int rr = 0; rr < 4; ++rr) {
                int m = bm + wm + i * 16 + kg * 4 + rr;
                int n = bn + wn + j * 16 + lr;
                float v1 = acc1[i][j][rr], v2 = acc2[i][j][rr];
                out[(size_t)m * N + n] = (bf16_t)(v1 / (1.f + __expf(-v1)) * v2);
            }
        }
    }
}

// ---------------------------------------------------------------------------
// Grouped gathered GLU for routed experts. Grid (N/128=8, 8 experts * 32
// tile-slots). Inactive tile-slots exit. A-rows gathered via tok_list.
// ---------------------------------------------------------------------------
__global__ __launch_bounds__(256) void glu_gather(
    const bf16_t* __restrict__ A, const bf16_t* __restrict__ W1,
    const bf16_t* __restrict__ W2, const int* __restrict__ tok_list,
    const int* __restrict__ cnt, const int* __restrict__ off,
    bf16_t* __restrict__ h)
{
    const int e = blockIdx.y >> 5, t = blockIdx.y & 31;
    const int ce = cnt[e];
    if (t * 128 >= ce) return;
    const int hbase = off[e] + t * 128;
    const bf16_t* W1e = W1 + (size_t)e * 1048576;
    const bf16_t* W2e = W2 + (size_t)e * 1048576;

    __shared__ __align__(16) bf16_t sA[128 * 64];
    __shared__ __align__(16) bf16_t sB1[128 * 64];
    __shared__ __align__(16) bf16_t sB2[128 * 64];
    const int tid  = threadIdx.x;
    const int bn   = blockIdx.x * 128;
    const int lane = tid & 63;
    const int wv   = tid >> 6;
    const int wm   = (wv >> 1) * 64, wn = (wv & 1) * 64;
    const int lr   = lane & 15;
    const int kg   = lane >> 4;

    int tok4[4];
    #pragma unroll
    for (int p = 0; p < 4; ++p)
        tok4[p] = tok_list[e * 4096 + t * 128 + p * 32 + (tid >> 3)];

    f32x4 acc1[4][4], acc2[4][4];
    #pragma unroll
    for (int i = 0; i < 4; ++i)
        #pragma unroll
        for (int j = 0; j < 4; ++j) {
            acc1[i][j] = f32x4{0.f, 0.f, 0.f, 0.f};
            acc2[i][j] = f32x4{0.f, 0.f, 0.f, 0.f};
        }

    for (int k0 = 0; k0 < 1024; k0 += 64) {
        #pragma unroll
        for (int p = 0; p < 4; ++p) {
            int idx = p * 256 + tid;
            int row = idx >> 3, ch = (idx & 7) * 8;
            GLD16(A   + (size_t)tok4[p] * 1024 + k0 + ch, sA  + idx * 8);
            GLD16(W1e + (size_t)(bn + row) * 1024 + k0 + ch, sB1 + idx * 8);
            GLD16(W2e + (size_t)(bn + row) * 1024 + k0 + ch, sB2 + idx * 8);
        }
        __syncthreads();
        #pragma unroll
        for (int ks = 0; ks < 2; ++ks) {
            bf16x8 af[4], b1[4], b2[4];
            #pragma unroll
            for (int i = 0; i < 4; ++i)
                af[i] = *(const bf16x8*)(sA + (wm + i * 16 + lr) * 64 + ks * 32 + kg * 8);
            #pragma unroll
            for (int j = 0; j < 4; ++j) {
                b1[j] = *(const bf16x8*)(sB1 + (wn + j * 16 + lr) * 64 + ks * 32 + kg * 8);
                b2[j] = *(const bf16x8*)(sB2 + (wn + j * 16 + lr) * 64 + ks * 32 + kg * 8);
            }
            #pragma unroll
            for (int i = 0; i < 4; ++i)
                #pragma unroll
                for (int j = 0; j < 4; ++j) {
                    acc1[i][j] = __builtin_amdgcn_mfma_f32_16x16x32_bf16(
                        af[i], b1[j], acc1[i][j], 0, 0, 0);
                    acc2[i][j] = __builtin_amdgcn_mfma_f32_16x16x32_bf16(
                        af[i], b2[j], acc2[i][j], 0, 0, 0);
                }
        }
        __syncthreads();
    }

    #pragma unroll
    for (int i = 0; i < 4; ++i) {
        #pragma unroll
        for (int j = 0; j < 4; ++j) {
            #pragma unroll
            for (int rr = 0; rr < 4; ++rr) {
                int rl = wm + i * 16 + kg * 4 + rr;
                int n  = bn + wn + j * 16 + lr;
                float v1 = acc1[i][j][rr], v2 = acc2[i][j][rr];
                h[(size_t)(hbase + rl) * 1024 + n] =
                    (bf16_t)(v1 / (1.f + __expf(-v1)) * v2);
            }
        }
    }
}

// ---------------------------------------------------------------------------
// Grouped down-proj with weighted scatter-add into y (atomicAdd fp32; each y
// element hit by at most 2 experts -> negligible contention).
// ---------------------------------------------------------------------------
__global__ __launch_bounds__(256) void down_gather(
    const bf16_t* __restrict__ h, const bf16_t* __restrict__ Wp,
    const int* __restrict__ tok_list, const float* __restrict__ w_list,
    const int* __restrict__ cnt, const int* __restrict__ off,
    float* __restrict__ y)
{
    const int e = blockIdx.y >> 5, t = blockIdx.y & 31;
    const int ce = cnt[e];
    if (t * 128 >= ce) return;
    const int hbase = off[e] + t * 128;
    const bf16_t* We = Wp + (size_t)e * 1048576;

    __shared__ __align__(16) bf16_t sA[128 * 64];
    __shared__ __align__(16) bf16_t sB[128 * 64];
    const int tid  = threadIdx.x;
    const int bn   = blockIdx.x * 128;
    const int lane = tid & 63;
    const int wv   = tid >> 6;
    const int wm   = (wv >> 1) * 64, wn = (wv & 1) * 64;
    const int lr   = lane & 15;
    const int kg   = lane >> 4;

    f32x4 acc[4][4];
    #pragma unroll
    for (int i = 0; i < 4; ++i)
        #pragma unroll
        for (int j = 0; j < 4; ++j)
            acc[i][j] = f32x4{0.f, 0.f, 0.f, 0.f};

    for (int k0 = 0; k0 < 1024; k0 += 64) {
        #pragma unroll
        for (int p = 0; p < 4; ++p) {
            int idx = p * 256 + tid;
            int row = idx >> 3, ch = (idx & 7) * 8;
            GLD16(h  + (size_t)(hbase + row) * 1024 + k0 + ch, sA + idx * 8);
            GLD16(We + (size_t)(bn + row) * 1024 + k0 + ch,    sB + idx * 8);
        }
        __syncthreads();
        #pragma unroll
        for (int ks = 0; ks < 2; ++ks) {
            bf16x8 af[4], bfr[4];
            #pragma unroll
            for (int i = 0; i < 4; ++i)
                af[i] = *(const bf16x8*)(sA + (wm + i * 16 + lr) * 64 + ks * 32 + kg * 8);
            #pragma unroll
            for (int j = 0; j < 4; ++j)
                bfr[j] = *(const bf16x8*)(sB + (wn + j * 16 + lr) * 64 + ks * 32 + kg * 8);
            #pragma unroll
            for (int i = 0; i < 4; ++i)
                #pragma unroll
                for (int j = 0; j < 4; ++j)
                    acc[i][j] = __builtin_amdgcn_mfma_f32_16x16x32_bf16(
                        af[i], bfr[j], acc[i][j], 0, 0, 0);
        }
        __syncthreads();
    }

    #pragma unroll
    for (int i = 0; i < 4; ++i) {
        #pragma unroll
        for (int rr = 0; rr < 4; ++rr) {
            int rl = t * 128 + wm + i * 16 + kg * 4 + rr;
            if (rl < ce) {
                int   tok = tok_list[e * 4096 + rl];
                float wgt = w_list[e * 4096 + rl];
                #pragma unroll
                for (int j = 0; j < 4; ++j) {
                    int n = bn + wn + j * 16 + lr;
                    atomicAdd(&y[(size_t)tok * 1024 + n], wgt * acc[i][j][rr]);
                }
            }
        }
    }
}

// ---------------------------------------------------------------------------
// RMSNorm: fp32 src -> bf16 dst, row length 1024 (used for norm1)
// ---------------------------------------------------------------------------
__global__ __launch_bounds__(256) void rmsnorm_k(
    const float* __restrict__ src, const float* __restrict__ w,
    bf16_t* __restrict__ dst)
{
    const int row = blockIdx.x, tid = threadIdx.x;
    float4 t4 = *((const float4*)src + (size_t)row * 256 + tid);
    float ssum = t4.x*t4.x + t4.y*t4.y + t4.z*t4.z + t4.w*t4.w;
    #pragma unroll
    for (int off = 32; off > 0; off >>= 1) ssum += __shfl_down(ssum, off);
    __shared__ float red[4];
    if ((tid & 63) == 0) red[tid >> 6] = ssum;
    __syncthreads();
    float total = red[0] + red[1] + red[2] + red[3];
    float rms = rsqrtf(total * (1.0f / 1024.0f) + 1e-6f);
    float4 w4 = *((const float4*)w + tid);
    bf16x4 o4;
    o4[0] = (bf16_t)(t4.x * rms * w4.x);
    o4[1] = (bf16_t)(t4.y * rms * w4.y);
    o4[2] = (bf16_t)(t4.z * rms * w4.z);
    o4[3] = (bf16_t)(t4.w * rms * w4.w);
    *((bf16x4*)dst + (size_t)row * 256 + tid) = o4;
}

// ---------------------------------------------------------------------------
// Fused RMSNorm + MoE gate. One block per token row. fp32 logits in-register
// (row already lives in registers); softmax + top-2 on lane 0; packed topi
// (i1 | i2<<8) + (w1,w2) per token. NO atomics.
// ---------------------------------------------------------------------------
__global__ __launch_bounds__(256) void rmsnorm_gate_k(
    const float* __restrict__ src, const float* __restrict__ w,
    const float* __restrict__ gw, bf16_t* __restrict__ dst,
    float* __restrict__ scores, int* __restrict__ topi,
    float* __restrict__ topw)
{
    const int row = blockIdx.x, tid = threadIdx.x;
    float4 t4 = *((const float4*)src + (size_t)row * 256 + tid);
    float ssum = t4.x*t4.x + t4.y*t4.y + t4.z*t4.z + t4.w*t4.w;
    #pragma unroll
    for (int off = 32; off > 0; off >>= 1) ssum += __shfl_down(ssum, off);
    __shared__ float red[4];
    if ((tid & 63) == 0) red[tid >> 6] = ssum;
    __syncthreads();
    float total = red[0] + red[1] + red[2] + red[3];
    float rms = rsqrtf(total * (1.0f / 1024.0f) + 1e-6f);
    float4 w4 = *((const float4*)w + tid);
    float4 f4;
    f4.x = t4.x * rms * w4.x;
    f4.y = t4.y * rms * w4.y;
    f4.z = t4.z * rms * w4.z;
    f4.w = t4.w * rms * w4.w;
    bf16x4 o4;
    o4[0] = (bf16_t)f4.x; o4[1] = (bf16_t)f4.y;
    o4[2] = (bf16_t)f4.z; o4[3] = (bf16_t)f4.w;
    *((bf16x4*)dst + (size_t)row * 256 + tid) = o4;

    // gate logits: per-thread dot over its 4 dims, then block reduce
    float a[8];
    #pragma unroll
    for (int e = 0; e < 8; ++e) {
        float4 g4 = *((const float4*)(gw + (size_t)e * 1024) + tid);
        a[e] = f4.x * g4.x + f4.y * g4.y + f4.z * g4.z + f4.w * g4.w;
    }
    #pragma unroll
    for (int e = 0; e < 8; ++e)
        #pragma unroll
        for (int off = 32; off > 0; off >>= 1) a[e] += __shfl_down(a[e], off);
    __shared__ float gred[4][8];
    if ((tid & 63) == 0)
        #pragma unroll
        for (int e = 0; e < 8; ++e) gred[tid >> 6][e] = a[e];
    __syncthreads();
    if (tid == 0) {
        float lg[8];
        #pragma unroll
        for (int e = 0; e < 8; ++e)
            lg[e] = gred[0][e] + gred[1][e] + gred[2][e] + gred[3][e];
        #pragma unroll
        for (int e = 0; e < 8; ++e) scores[(size_t)row * 8 + e] = lg[e];
        float mx = lg[0];
        #pragma unroll
        for (int e = 1; e < 8; ++e) mx = fmaxf(mx, lg[e]);
        float p[8], sum = 0.f;
        #pragma unroll
        for (int e = 0; e < 8; ++e) { p[e] = __expf(lg[e] - mx); sum += p[e]; }
        float inv = 1.0f / sum;
        #pragma unroll
        for (int e = 0; e < 8; ++e) p[e] *= inv;
        int i1 = 0;
        #pragma unroll
        for (int e = 1; e < 8; ++e) if (p[e] > p[i1]) i1 = e;
        int i2 = (i1 == 0) ? 1 : 0;
        #pragma unroll
        for (int e = 0; e < 8; ++e) if (e != i1 && p[e] > p[i2]) i2 = e;
        topi[row] = i1 | (i2 << 8);
        topw[row * 2]     = p[i1];
        topw[row * 2 + 1] = p[i2];
    }
}

// ---------------------------------------------------------------------------
// Build per-expert token lists WITHOUT atomics: one block per expert (owns
// its list), 16 rounds of ballot + prefix over the 4096 packed topi words.
// Emits ascending-token compacted lists, pads tail tile with token 0.
// ---------------------------------------------------------------------------
__global__ __launch_bounds__(256) void build_lists_k(
    const int* __restrict__ topi, const float* __restrict__ topw,
    int* __restrict__ tok_list, float* __restrict__ w_list,
    int* __restrict__ cnt)
{
    const int e = blockIdx.x;
    const int tid = threadIdx.x, lane = tid & 63, wv = tid >> 6;
    __shared__ int wc[4];
    int base = 0;
    for (int t0 = 0; t0 < 4096; t0 += 256) {
        int tok = t0 + tid;
        int ti = topi[tok];
        int i1 = ti & 255, i2 = (ti >> 8) & 255;
        bool m = (i1 == e) || (i2 == e);
        unsigned long long b = __ballot(m);
        if (lane == 0) wc[wv] = __popcll(b);
        __syncthreads();
        int pos = base;
        #pragma unroll
        for (int k = 0; k < 4; ++k) if (k < wv) pos += wc[k];
        pos += __popcll(b & ((1ull << lane) - 1ull));
        if (m) {
            tok_list[e * 4096 + pos] = tok;
            w_list[e * 4096 + pos]   = (i1 == e) ? topw[tok * 2] : topw[tok * 2 + 1];
        }
        base += wc[0] + wc[1] + wc[2] + wc[3];
        __syncthreads();
    }
    int padded = (base + 127) & ~127;
    for (int p = base + tid; p < padded; p += 256) tok_list[e * 4096 + p] = 0;
    if (tid == 0) cnt[e] = base;
}

// ---------------------------------------------------------------------------
// Routing plan: 128-padded prefix offsets per expert (total <= 9216 rows)
// ---------------------------------------------------------------------------
__global__ void plan_k(const int* __restrict__ cnt, int* __restrict__ off)
{
    if (threadIdx.x == 0) {
        int run = 0;
        for (int e = 0; e < 8; ++e) {
            off[e] = run;
            run += (cnt[e] + 127) & ~127;
        }
    }
}

// ---------------------------------------------------------------------------
// RoPE in-place on bf16 buffer (4096 x nh*64); freq fp32 (1024 x 32 x 2)
// ---------------------------------------------------------------------------
__global__ __launch_bounds__(256) void rope_k(
    bf16_t* __restrict__ buf, const float* __restrict__ fc, int nh)
{
    int idx = blockIdx.x * 256 + threadIdx.x;
    int pr = idx & 31;
    int hn = idx >> 5;
    int h  = hn % nh;
    int n  = hn / nh;
    int tpos = n & 1023;
    const float* f = fc + ((size_t)tpos * 32 + pr) * 2;
    float c = f[0], s = f[1];
    size_t base = ((size_t)n * nh + h) * 64 + pr * 2;
    float x0 = (float)buf[base], x1 = (float)buf[base + 1];
    buf[base]     = (bf16_t)(x0 * c - x1 * s);
    buf[base + 1] = (bf16_t)(x1 * c + x0 * s);
}

// ---------------------------------------------------------------------------
// V transpose: vb (4096 x 256, [token][kvh*64+d]) -> vt [(b*4+kvh)*64+d][1024]
// ---------------------------------------------------------------------------
__global__ __launch_bounds__(256) void transpose_v(
    const bf16_t* __restrict__ vb, bf16_t* __restrict__ vt)
{
    __shared__ bf16_t tile[64][72];
    const int tt = blockIdx.x, kvh = blockIdx.y, b = blockIdx.z;
    const int tid = threadIdx.x;
    {
        int r = tid >> 2, c = (tid & 3) * 16;
        const bf16_t* src = vb + ((size_t)(b * 1024 + tt * 64 + r)) * 256 + kvh * 64 + c;
        bf16x8 v0 = *(const bf16x8*)src;
        bf16x8 v1 = *(const bf16x8*)(src + 8);
        *(bf16x8*)&tile[r][c] = v0;
        *(bf16x8*)&tile[r][c + 8] = v1;
    }
    __syncthreads();
    {
        int d = tid >> 2, t4 = (tid & 3) * 16;
        bf16_t* dst = vt + ((size_t)((b * 4 + kvh) * 64 + d)) * 1024 + tt * 64 + t4;
        bf16x8 o0, o1;
        #pragma unroll
        for (int u = 0; u < 8; ++u) {
            o0[u] = tile[t4 + u][d];
            o1[u] = tile[t4 + 8 + u][d];
        }
        *(bf16x8*)dst = o0;
        *(bf16x8*)(dst + 8) = o1;
    }
}

// ---------------------------------------------------------------------------
// MFMA flash attention, causal GQA. Grid (qt=16, h=16, b=4), 256 thr = 4 waves.
// ---------------------------------------------------------------------------
__global__ __launch_bounds__(256) void attn_mfma(
    const bf16_t* __restrict__ qb, const bf16_t* __restrict__ kb,
    const bf16_t* __restrict__ vt, bf16_t* __restrict__ ob)
{
    const int qt = blockIdx.x, h = blockIdx.y, b = blockIdx.z;
    const int kvh = h >> 2;
    __shared__ __align__(16) bf16_t sK[64 * 64];
    __shared__ __align__(16) bf16_t sVt[64 * 64];
    __shared__ __align__(16) bf16_t sP[64 * 72];
    const int tid  = threadIdx.x;
    const int w    = tid >> 6;
    const int lane = tid & 63;
    const int lr   = lane & 15;
    const int kg   = lane >> 4;

    bf16x8 qf[2];
    {
        const bf16_t* qrow = qb + ((size_t)(b * 1024 + qt * 64 + w * 16 + lr)) * 1024 + h * 64;
        qf[0] = *(const bf16x8*)(qrow + kg * 8);
        qf[1] = *(const bf16x8*)(qrow + 32 + kg * 8);
    }
    float m_run[4], l_run[4];
    f32x4 o_acc[4];
    #pragma unroll
    for (int rr = 0; rr < 4; ++rr) { m_run[rr] = -1.0e30f; l_run[rr] = 0.f; }
    #pragma unroll
    for (int dt = 0; dt < 4; ++dt) o_acc[dt] = f32x4{0.f, 0.f, 0.f, 0.f};

    for (int kt = 0; kt <= qt; ++kt) {
        #pragma unroll
        for (int p = 0; p < 2; ++p) {
            int idx = p * 256 + tid;
            int row = idx >> 3, ch = (idx & 7) * 8;
            GLD16(kb + ((size_t)(b * 1024 + kt * 64 + row)) * 256 + kvh * 64 + ch,
                  sK + idx * 8);
            GLD16(vt + ((size_t)((b * 4 + kvh) * 64 + row)) * 1024 + kt * 64 + ch,
                  sVt + idx * 8);
        }
        __syncthreads();

        f32x4 sfr[4];
        #pragma unroll
        for (int j = 0; j < 4; ++j) {
            sfr[j] = f32x4{0.f, 0.f, 0.f, 0.f};
            #pragma unroll
            for (int ks = 0; ks < 2; ++ks) {
                bf16x8 bf = *(const bf16x8*)(sK + (j * 16 + lr) * 64 + ks * 32 + kg * 8);
                sfr[j] = __builtin_amdgcn_mfma_f32_16x16x32_bf16(qf[ks], bf, sfr[j], 0, 0, 0);
            }
        }
        const int rowg = qt * 64 + w * 16 + kg * 4;
        float mnew[4];
        #pragma unroll
        for (int rr = 0; rr < 4; ++rr) mnew[rr] = m_run[rr];
        #pragma unroll
        for (int j = 0; j < 4; ++j) {
            int colg = kt * 64 + j * 16 + lr;
            #pragma unroll
            for (int rr = 0; rr < 4; ++rr) {
                float s = sfr[j][rr] * 0.125f;
                if (colg > rowg + rr) s = -1.0e30f;
                sfr[j][rr] = s;
                mnew[rr] = fmaxf(mnew[rr], s);
            }
        }
        #pragma unroll
        for (int off = 1; off < 16; off <<= 1)
            #pragma unroll
            for (int rr = 0; rr < 4; ++rr)
                mnew[rr] = fmaxf(mnew[rr], __shfl_xor(mnew[rr], off, 64));
        float alpha[4], lpart[4];
        #pragma unroll
        for (int rr = 0; rr < 4; ++rr) {
            alpha[rr] = __expf(m_run[rr] - mnew[rr]);
            lpart[rr] = 0.f;
        }
        #pragma unroll
        for (int j = 0; j < 4; ++j)
            #pragma unroll
            for (int rr = 0; rr < 4; ++rr) {
                float p = __expf(sfr[j][rr] - mnew[rr]);
                sfr[j][rr] = p;
                lpart[rr] += p;
            }
        #pragma unroll
        for (int j = 0; j < 4; ++j)
            #pragma unroll
            for (int rr = 0; rr < 4; ++rr)
                sP[(w * 16 + kg * 4 + rr) * 72 + j * 16 + lr] = (bf16_t)sfr[j][rr];
        #pragma unroll
        for (int off = 1; off < 16; off <<= 1)
            #pragma unroll
            for (int rr = 0; rr < 4; ++rr)
                lpart[rr] += __shfl_xor(lpart[rr], off, 64);
        #pragma unroll
        for (int rr = 0; rr < 4; ++rr) {
            l_run[rr] = l_run[rr] * alpha[rr] + lpart[rr];
            m_run[rr] = mnew[rr];
        }
        #pragma unroll
        for (int dt = 0; dt < 4; ++dt)
            #pragma unroll
            for (int rr = 0; rr < 4; ++rr)
                o_acc[dt][rr] *= alpha[rr];
        #pragma unroll
        for (int ks = 0; ks < 2; ++ks) {
            bf16x8 af = *(const bf16x8*)(sP + (w * 16 + lr) * 72 + ks * 32 + kg * 8);
            #pragma unroll
            for (int dt = 0; dt < 4; ++dt) {
                bf16x8 bf = *(const bf16x8*)(sVt + (dt * 16 + lr) * 64 + ks * 32 + kg * 8);
                o_acc[dt] = __builtin_amdgcn_mfma_f32_16x16x32_bf16(af, bf, o_acc[dt], 0, 0, 0);
            }
        }
        __syncthreads();
    }

    float inv[4];
    #pragma unroll
    for (int rr = 0; rr < 4; ++rr) inv[rr] = 1.0f / l_run[rr];
    #pragma unroll
    for (int dt = 0; dt < 4; ++dt)
        #pragma unroll
        for (int rr = 0; rr < 4; ++rr) {
            int tok = qt * 64 + w * 16 + kg * 4 + rr;
            ob[((size_t)(b * 1024 + tok)) * 1024 + h * 64 + dt * 16 + lr] =
                (bf16_t)(o_acc[dt][rr] * inv[rr]);
        }
}

// ---------------------------------------------------------------------------
// out = x1 + y (fp32)
// ---------------------------------------------------------------------------
__global__ __launch_bounds__(256) void finalize_k(
    const float* __restrict__ x1, const float* __restrict__ y, float* __restrict__ out)
{
    size_t i = (size_t)blockIdx.x * 256 + threadIdx.x;
    float4 a = *((const float4*)x1 + i);
    float4 b = *((const float4*)y + i);
    float4 o4;
    o4.x = a.x + b.x; o4.y = a.y + b.y; o4.z = a.z + b.z; o4.w = a.w + b.w;
    *((float4*)out + i) = o4;
}

// ---------------------------------------------------------------------------
extern "C" void kernel_launch(void* const* d_in, const int* in_sizes, int n_in,
                              void* d_out, int out_size, void* d_ws, size_t ws_size,
                              hipStream_t stream)
{
    const float* x   = (const float*)d_in[0];
    const float* fc  = (const float*)d_in[1];
    const float* n1w = (const float*)d_in[4];
    const float* wq  = (const float*)d_in[5];
    const float* wk  = (const float*)d_in[6];
    const float* wv  = (const float*)d_in[7];
    const float* wo  = (const float*)d_in[8];
    const float* n2w = (const float*)d_in[9];
    const float* gw  = (const float*)d_in[10];
    const float* ew1 = (const float*)d_in[11];
    const float* ew2 = (const float*)d_in[12];
    const float* ewp = (const float*)d_in[13];
    const float* sw1 = (const float*)d_in[14];
    const float* sw2 = (const float*)d_in[15];
    const float* swp = (const float*)d_in[16];

    // ---- workspace (peak ~97 MB; phase-aliased) ----
    const size_t MB = 1024 * 1024;
    char* ws = (char*)d_ws;
    bf16_t* xnb  = (bf16_t*)(ws + 0);        // [0,8)   xn / xn2 bf16
    float*  x1   = (float*) (ws + 8 * MB);   // [8,24)  residual-1 fp32
    float*  y    = (float*) (ws + 24 * MB);  // [24,40) MoE accum fp32
    char*   slotA= ws + 40 * MB;             // [40,56) attn-w | sh-hb | ew1b | ewpb
    bf16_t* h    = (bf16_t*)(ws + 56 * MB);  // [56,74) expert GLU out (9216 x 1024)
    char*   lists= ws + 74 * MB;             // [74,75) routing lists
    int*    tok_list = (int*)lists;                   // 8*4096 int
    float*  w_list   = (float*)(lists + 131072);      // 8*4096 float
    int*    cnt      = (int*)(lists + 262144);        // 8 int
    int*    off      = (int*)(lists + 262208);        // 8 int
    int*    topi     = (int*)(lists + 262400);        // 4096 int
    float*  topw     = (float*)(lists + 278784);      // 4096 float2
    bf16_t* qb   = (bf16_t*)(ws + 75 * MB);  // [75,83) attn phase
    bf16_t* kb   = (bf16_t*)(ws + 83 * MB);  // [83,85)
    bf16_t* vb   = (bf16_t*)(ws + 85 * MB);  // [85,87)
    bf16_t* ob   = (bf16_t*)(ws + 87 * MB);  // [87,95)
    bf16_t* vt   = (bf16_t*)(ws + 95 * MB);  // [95,97) V transposed

    float* outp   = (float*)d_out;
    float* scores = outp + (size_t)4096 * 1024;

    auto conv = [&](const float* s, bf16_t* d, size_t cntN) {
        convert_k<<<cntN / 1024, 256, 0, stream>>>(s, d);
    };
    auto gemm = [&](const bf16_t* A, const bf16_t* W, int M, int N, int K, int ldw,
                    int mode, float* oF, bf16_t* oB, const float* res) {
        gemm_bt<<<dim3(N / 128, M / 128), 256, 0, stream>>>(
            A, W, M, N, K, ldw, mode, oF, oB, res);
    };
    auto glu = [&](const bf16_t* A, const bf16_t* W1, const bf16_t* W2,
                   int M, int N, int K, bf16_t* o) {
        gemm_glu<<<dim3(N / 128, M / 128), 256, 0, stream>>>(A, W1, W2, M, N, K, o);
    };

    // ---- attention ----
    bf16_t* wqb = (bf16_t*)slotA;            // dead after O-proj GEMM
    bf16_t* wkb = wqb + 1048576;
    bf16_t* wvb = wkb + 262144;
    bf16_t* wob = wvb + 262144;
    conv(wq, wqb, 1048576);
    conv(wk, wkb, 262144);
    conv(wv, wvb, 262144);
    conv(wo, wob, 1048576);

    rmsnorm_k<<<4096, 256, 0, stream>>>(x, n1w, xnb);
    gemm(xnb, wqb, 4096, 1024, 1024, 1024, 1, nullptr, qb, nullptr);
    gemm(xnb, wkb, 4096, 256, 1024, 1024, 1, nullptr, kb, nullptr);
    gemm(xnb, wvb, 4096, 256, 1024, 1024, 1, nullptr, vb, nullptr);
    rope_k<<<(4096 * 16 * 32) / 256, 256, 0, stream>>>(qb, fc, 16);
    rope_k<<<(4096 * 4 * 32) / 256, 256, 0, stream>>>(kb, fc, 4);
    transpose_v<<<dim3(16, 4, 4), 256, 0, stream>>>(vb, vt);
    attn_mfma<<<dim3(16, 16, 4), 256, 0, stream>>>(qb, kb, vt, ob);
    gemm(ob, wob, 4096, 1024, 1024, 1024, 2, x1, nullptr, x);

    // ---- MoE: fused norm2+gate, atomics-free list build, plan ----
    rmsnorm_gate_k<<<4096, 256, 0, stream>>>(x1, n2w, gw, xnb, scores, topi, topw);
    build_lists_k<<<8, 256, 0, stream>>>(topi, topw, tok_list, w_list, cnt);
    plan_k<<<1, 64, 0, stream>>>(cnt, off);

    // ---- shared expert (dense) ----
    bf16_t* sw1b = (bf16_t*)(ws + 75 * MB);  // overwrites attn bufs (dead)
    bf16_t* sw2b = sw1b + 2097152;
    bf16_t* swpb = sw2b + 2097152;
    conv(sw1, sw1b, 2097152);
    conv(sw2, sw2b, 2097152);
    conv(swp, swpb, 2097152);
    bf16_t* hb = (bf16_t*)slotA;             // overwrites attn weights (dead)
    glu(xnb, sw1b, sw2b, 4096, 2048, 1024, hb);
    gemm(hb, swpb, 4096, 1024, 2048, 2048, 0, y, nullptr, nullptr);

    // ---- routed experts (sparse, grouped single launches) ----
    bf16_t* ew1b = (bf16_t*)slotA;           // overwrites shared hb (dead)
    bf16_t* ew2b = (bf16_t*)(ws + 75 * MB);  // overwrites shared weights (dead)
    conv(ew1, ew1b, 8388608);
    conv(ew2, ew2b, 8388608);
    glu_gather<<<dim3(8, 256), 256, 0, stream>>>(xnb, ew1b, ew2b,
                                                 tok_list, cnt, off, h);
    bf16_t* ewpb = (bf16_t*)slotA;           // overwrites ew1b (dead after GLU)
    conv(ewp, ewpb, 8388608);
    down_gather<<<dim3(8, 256), 256, 0, stream>>>(h, ewpb,
                                                  tok_list, w_list, cnt, off, y);

    finalize_k<<<(4096 * 1024) / 1024, 256, 0, stream>>>(x1, y, outp);
    (void)in_sizes; (void)n_in; (void)out_size; (void)ws_size;
}